// Round 6
// baseline (305.741 us; speedup 1.0000x reference)
//
#include <hip/hip_runtime.h>
#include <hip/hip_bf16.h>

#define B_ 2
#define T_ 2048
#define D_ 1024
#define H_ 16
#define HD_ 64
#define NP_ 3
#define P_ 256

// log2(e)/sqrt(64): softmax runs in exp2 domain
#define SCALE2 0.18033688011112042f

typedef short bf16x8 __attribute__((ext_vector_type(8)));
typedef float f32x4 __attribute__((ext_vector_type(4)));

__device__ __forceinline__ float bf2f(__hip_bfloat16 v) { return __bfloat162float(v); }
__device__ __forceinline__ __hip_bfloat16 f2bf(float v) { return __float2bfloat16(v); }

#define GLOAD_LDS16(gp, lp) \
    __builtin_amdgcn_global_load_lds( \
        (const __attribute__((address_space(1))) void*)(gp), \
        (__attribute__((address_space(3))) void*)(lp), 16, 0, 0)

// ---------------------------------------------------------------------------
// Kernel 0: input dtype detect + work-queue counter reset (every launch).
// ---------------------------------------------------------------------------
__global__ __launch_bounds__(256) void detect_kernel(
    const unsigned short* __restrict__ xs, int* __restrict__ flag,
    int* __restrict__ counter)
{
    __shared__ int cnt;
    if (threadIdx.x == 0) cnt = 0;
    __syncthreads();
    int bad = 0;
    for (int i = threadIdx.x; i < 16384; i += 256) {
        int e = (xs[i] >> 7) & 0xFF;
        if (e >= 0xB8) bad++;
    }
    if (bad) atomicAdd(&cnt, bad);
    __syncthreads();
    if (threadIdx.x == 0) { *flag = (cnt >= 8) ? 1 : 0; *counter = 0; }
}

// fp32-or-bf16 -> bf16 (weights for MFMA)
__global__ __launch_bounds__(256) void cvt16_kernel(
    const void* __restrict__ src, __hip_bfloat16* __restrict__ dst,
    int n, const int* __restrict__ flag)
{
    int i = blockIdx.x * 256 + threadIdx.x;
    if (i >= n) return;
    dst[i] = (*flag) ? f2bf(((const float*)src)[i])
                     : ((const __hip_bfloat16*)src)[i];
}

// all 7 small fp32 parameter arrays in one launch -> contiguous fp32 block
__global__ __launch_bounds__(256) void cvt_small_kernel(
    const void* __restrict__ g,  const void* __restrict__ b,
    const void* __restrict__ n1, const void* __restrict__ n2,
    const void* __restrict__ ang, const void* __restrict__ gt,
    const void* __restrict__ bi,
    float* __restrict__ dst, const int* __restrict__ flag)
{
    int i = blockIdx.x * 256 + threadIdx.x;
    if (i >= 11008) return;
    const void* src; int off;
    if      (i < 1024) { src = g;   off = i; }
    else if (i < 2048) { src = b;   off = i - 1024; }
    else if (i < 3072) { src = n1;  off = i - 2048; }
    else if (i < 4096) { src = n2;  off = i - 3072; }
    else if (i < 4864) { src = ang; off = i - 4096; }
    else if (i < 7936) { src = gt;  off = i - 4864; }
    else               { src = bi;  off = i - 7936; }
    dst[i] = (*flag) ? ((const float*)src)[off]
                     : bf2f(((const __hip_bfloat16*)src)[off]);
}

// ---------------------------------------------------------------------------
// Kernel 1: h = rmsnorm(x,w)*gamma+beta (bf16 out) and xcopy = x as fp32.
// ---------------------------------------------------------------------------
__global__ __launch_bounds__(256) void rmsnorm1_kernel(
    const void* __restrict__ xraw,
    const float* __restrict__ gamma,
    const float* __restrict__ beta,
    const float* __restrict__ w,
    const int* __restrict__ flag,
    __hip_bfloat16* __restrict__ out,
    float* __restrict__ xcopy)
{
    int row = blockIdx.x;
    int t = threadIdx.x;
    int f = *flag;
    float eps = f ? 1.1920929e-7f : 0.0078125f;
    float v[4];
    if (f) {
        const float4 xv = ((const float4*)((const float*)xraw + (size_t)row * D_))[t];
        v[0] = xv.x; v[1] = xv.y; v[2] = xv.z; v[3] = xv.w;
    } else {
        const __hip_bfloat16* xr = (const __hip_bfloat16*)xraw + (size_t)row * D_;
#pragma unroll
        for (int c = 0; c < 4; c++) v[c] = bf2f(xr[t * 4 + c]);
    }
    float ss = 0.f;
#pragma unroll
    for (int c = 0; c < 4; c++) ss += v[c] * v[c];
#pragma unroll
    for (int m = 32; m; m >>= 1) ss += __shfl_xor(ss, m, 64);
    __shared__ float red[4];
    int wv = t >> 6;
    if ((t & 63) == 0) red[wv] = ss;
    __syncthreads();
    float scale = rsqrtf((red[0] + red[1] + red[2] + red[3]) * (1.0f / D_) + eps);
#pragma unroll
    for (int c = 0; c < 4; c++) {
        int e = t * 4 + c;
        size_t idx = (size_t)row * D_ + e;
        xcopy[idx] = v[c];
        out[idx] = f2bf(v[c] * scale * w[e] * gamma[e] + beta[e]);
    }
}

// ---------------------------------------------------------------------------
// Kernel 2: C = A @ B^T bf16 out. 128x128, BK=32, global_load_lds width=16.
// ---------------------------------------------------------------------------
__global__ __launch_bounds__(256) void gemm_bt_bf16_kernel(
    const __hip_bfloat16* __restrict__ A,
    const __hip_bfloat16* __restrict__ Bm,
    __hip_bfloat16* __restrict__ C,
    int M, int N, int K)
{
    __shared__ __attribute__((aligned(16))) __hip_bfloat16 As[128 * 32];
    __shared__ __attribute__((aligned(16))) __hip_bfloat16 Bs[128 * 32];
    int tid = threadIdx.x;
    int bm = blockIdx.y, bn = blockIdx.x;
    int lane = tid & 63, wv = tid >> 6;
    int wm = wv >> 1, wn = wv & 1;
    int q = lane >> 4, mr = lane & 15;

    f32x4 acc[4][4] = {};

    for (int k0 = 0; k0 < K; k0 += 32) {
#pragma unroll
        for (int s = 0; s < 2; s++) {
            int e = (s * 256 + tid) * 8;
            int r = e >> 5, c = e & 31;
            GLOAD_LDS16(&A[(size_t)(bm * 128 + r) * K + k0 + c], &As[e]);
            GLOAD_LDS16(&Bm[(size_t)(bn * 128 + r) * K + k0 + c], &Bs[e]);
        }
        __syncthreads();
        bf16x8 af[4], bfr[4];
#pragma unroll
        for (int i = 0; i < 4; i++)
            af[i] = *(const bf16x8*)(&As[(wm * 64 + i * 16 + mr) * 32 + q * 8]);
#pragma unroll
        for (int j = 0; j < 4; j++)
            bfr[j] = *(const bf16x8*)(&Bs[(wn * 64 + j * 16 + mr) * 32 + q * 8]);
#pragma unroll
        for (int i = 0; i < 4; i++)
#pragma unroll
            for (int j = 0; j < 4; j++)
                acc[i][j] = __builtin_amdgcn_mfma_f32_16x16x32_bf16(af[i], bfr[j], acc[i][j], 0, 0, 0);
        __syncthreads();
    }

#pragma unroll
    for (int i = 0; i < 4; i++)
#pragma unroll
        for (int r = 0; r < 4; r++) {
            int m = bm * 128 + wm * 64 + i * 16 + q * 4 + r;
#pragma unroll
            for (int j = 0; j < 4; j++) {
                int n = bn * 128 + wn * 64 + j * 16 + mr;
                C[(size_t)m * N + n] = f2bf(acc[i][j][r]);
            }
        }
}

// Same GEMM, fp32 residual in + fp32 out (o-proj + residual spine).
__global__ __launch_bounds__(256) void gemm_bt_resid_kernel(
    const __hip_bfloat16* __restrict__ A,
    const __hip_bfloat16* __restrict__ Bm,
    const float* __restrict__ resid,
    float* __restrict__ C,
    int M, int N, int K)
{
    __shared__ __attribute__((aligned(16))) __hip_bfloat16 As[128 * 32];
    __shared__ __attribute__((aligned(16))) __hip_bfloat16 Bs[128 * 32];
    int tid = threadIdx.x;
    int bm = blockIdx.y, bn = blockIdx.x;
    int lane = tid & 63, wv = tid >> 6;
    int wm = wv >> 1, wn = wv & 1;
    int q = lane >> 4, mr = lane & 15;

    f32x4 acc[4][4] = {};

    for (int k0 = 0; k0 < K; k0 += 32) {
#pragma unroll
        for (int s = 0; s < 2; s++) {
            int e = (s * 256 + tid) * 8;
            int r = e >> 5, c = e & 31;
            GLOAD_LDS16(&A[(size_t)(bm * 128 + r) * K + k0 + c], &As[e]);
            GLOAD_LDS16(&Bm[(size_t)(bn * 128 + r) * K + k0 + c], &Bs[e]);
        }
        __syncthreads();
        bf16x8 af[4], bfr[4];
#pragma unroll
        for (int i = 0; i < 4; i++)
            af[i] = *(const bf16x8*)(&As[(wm * 64 + i * 16 + mr) * 32 + q * 8]);
#pragma unroll
        for (int j = 0; j < 4; j++)
            bfr[j] = *(const bf16x8*)(&Bs[(wn * 64 + j * 16 + mr) * 32 + q * 8]);
#pragma unroll
        for (int i = 0; i < 4; i++)
#pragma unroll
            for (int j = 0; j < 4; j++)
                acc[i][j] = __builtin_amdgcn_mfma_f32_16x16x32_bf16(af[i], bfr[j], acc[i][j], 0, 0, 0);
        __syncthreads();
    }

#pragma unroll
    for (int i = 0; i < 4; i++)
#pragma unroll
        for (int r = 0; r < 4; r++) {
            int m = bm * 128 + wm * 64 + i * 16 + q * 4 + r;
#pragma unroll
            for (int j = 0; j < 4; j++) {
                int n = bn * 128 + wn * 64 + j * 16 + mr;
                size_t idx = (size_t)m * N + n;
                C[idx] = resid[idx] + acc[i][j][r];
            }
        }
}

// ---------------------------------------------------------------------------
// Kernel 3: causal flash attention, persistent blocks + work-stealing.
// Jobs (heavy-first):
//   j in [0,1024):    qt = 31-(j>>6) (>=16), bh=(j&63)>>1, half=j&1 -> key-split
//   j in [1024,1536): qt = 15-((j-1024)>>5), bh=(j-1024)&31, whole
// Split jobs write unnormalized partials (o bf16, m/l fp32) for merge kernel.
// Single-buffer K/V (24 KB LDS) -> 4 blocks/CU with 1024 persistent blocks.
// XOR chunk swizzle (verified, 0 conflicts). Softmax in exp2 domain.
// ---------------------------------------------------------------------------
__global__ __launch_bounds__(256, 4) void attn_kernel(
    const __hip_bfloat16* __restrict__ qkv,
    __hip_bfloat16* __restrict__ attn_out,
    int* __restrict__ counter,
    __hip_bfloat16* __restrict__ obuf,   // [512][2][64][64]
    float* __restrict__ mbuf,            // [512][2][64]
    float* __restrict__ lbuf)            // [512][2][64]
{
    __shared__ __attribute__((aligned(16))) __hip_bfloat16 Ks[64 * 64];
    __shared__ __attribute__((aligned(16))) __hip_bfloat16 Vts[64 * 64]; // [dim][key]
    __shared__ __attribute__((aligned(16))) __hip_bfloat16 Ps[4 * 16 * 64];
    __shared__ int sj;

    int tid = threadIdx.x, lane = tid & 63, wv = tid >> 6;
    int q = lane >> 4, mr = lane & 15;
    int m8 = mr & 7;

    // staging roles
    int sr = tid >> 2;              // K row (key) 0..63
    int sc = (tid & 3) * 16;        // K col start
    int lc0 = sc >> 3;
    int swk = sr & 7;
    int kk_ = (tid & 31) * 2;       // V key (even)
    int dd = (tid >> 5) * 8;        // V dim chunk base
    int vlc = kk_ >> 3, voff = kk_ & 7;

    for (;;) {
        if (tid == 0) sj = atomicAdd(counter, 1);
        __syncthreads();            // broadcast sj; all waves done with LDS
        int j = sj;
        if (j >= 1536) break;

        int qt, bh, k0t, k1t, half, split;
        if (j < 1024) {
            split = 1; qt = 31 - (j >> 6);
            int rem = j & 63; bh = rem >> 1; half = rem & 1;
            int nk0 = (qt + 2) >> 1;
            k0t = half ? nk0 : 0;
            k1t = half ? qt + 1 : nk0;
        } else {
            split = 0; half = 0;
            int jj = j - 1024;
            qt = 15 - (jj >> 5); bh = jj & 31;
            k0t = 0; k1t = qt + 1;
        }
        int b = bh >> 4, h = bh & 15;
        const size_t rs3 = 3 * D_;
        const __hip_bfloat16* qp = qkv + (size_t)(b * T_) * rs3 + h * HD_;
        const __hip_bfloat16* kp = qp + D_;
        const __hip_bfloat16* vp = qp + 2 * D_;

        // Q fragments (wave-private 16 rows)
        const __hip_bfloat16* qrow = qp + (size_t)(qt * 64 + wv * 16 + mr) * rs3;
        bf16x8 aq0 = *(const bf16x8*)(qrow + q * 8);
        bf16x8 aq1 = *(const bf16x8*)(qrow + 32 + q * 8);

        // prefetch first K/V tile
        bf16x8 kr0 = *(const bf16x8*)(kp + (size_t)(k0t * 64 + sr) * rs3 + sc);
        bf16x8 kr1 = *(const bf16x8*)(kp + (size_t)(k0t * 64 + sr) * rs3 + sc + 8);
        bf16x8 vr0 = *(const bf16x8*)(vp + (size_t)(k0t * 64 + kk_) * rs3 + dd);
        bf16x8 vr1 = *(const bf16x8*)(vp + (size_t)(k0t * 64 + kk_ + 1) * rs3 + dd);

        float m_run[4], l_run[4];
        f32x4 o_acc[4] = {};
#pragma unroll
        for (int r = 0; r < 4; r++) { m_run[r] = -INFINITY; l_run[r] = 0.f; }

        for (int kt = k0t; kt < k1t; kt++) {
            __syncthreads();   // previous compute done
            *(bf16x8*)(&Ks[sr * 64 + ((lc0 ^ swk) * 8)]) = kr0;
            *(bf16x8*)(&Ks[sr * 64 + (((lc0 + 1) ^ swk) * 8)]) = kr1;
            {
                unsigned int* vd = (unsigned int*)Vts;
#pragma unroll
                for (int i = 0; i < 8; i++) {
                    unsigned int wd = ((unsigned int)(unsigned short)vr0[i]) |
                                      (((unsigned int)(unsigned short)vr1[i]) << 16);
                    vd[((dd + i) * 64 + ((vlc ^ i) * 8 + voff)) >> 1] = wd;
                }
            }
            __syncthreads();   // staging visible
            if (kt + 1 < k1t) {   // prefetch next tile (hidden under compute)
                kr0 = *(const bf16x8*)(kp + (size_t)((kt + 1) * 64 + sr) * rs3 + sc);
                kr1 = *(const bf16x8*)(kp + (size_t)((kt + 1) * 64 + sr) * rs3 + sc + 8);
                vr0 = *(const bf16x8*)(vp + (size_t)((kt + 1) * 64 + kk_) * rs3 + dd);
                vr1 = *(const bf16x8*)(vp + (size_t)((kt + 1) * 64 + kk_ + 1) * rs3 + dd);
            }

            // S strip = Q[wv*16..+16) @ K^T
            f32x4 sv[4] = {};
#pragma unroll
            for (int jn = 0; jn < 4; jn++)
                sv[jn] = __builtin_amdgcn_mfma_f32_16x16x32_bf16(aq0,
                    *(const bf16x8*)(&Ks[(jn * 16 + mr) * 64 + ((q ^ m8) * 8)]), sv[jn], 0, 0, 0);
#pragma unroll
            for (int jn = 0; jn < 4; jn++)
                sv[jn] = __builtin_amdgcn_mfma_f32_16x16x32_bf16(aq1,
                    *(const bf16x8*)(&Ks[(jn * 16 + mr) * 64 + (((4 + q) ^ m8) * 8)]), sv[jn], 0, 0, 0);

            bool diag = (kt == qt);
#pragma unroll
            for (int jn = 0; jn < 4; jn++)
#pragma unroll
                for (int r = 0; r < 4; r++) {
                    float x = sv[jn][r] * SCALE2;   // exp2 domain
                    if (diag) {
                        int rowg = wv * 16 + q * 4 + r;
                        int colg = jn * 16 + mr;
                        if (colg > rowg) x = -1e30f;
                    }
                    sv[jn][r] = x;
                }

            // online softmax per query row (16 mr-lanes share a row, fixed q)
#pragma unroll
            for (int r = 0; r < 4; r++) {
                float m0 = fmaxf(fmaxf(sv[0][r], sv[1][r]), fmaxf(sv[2][r], sv[3][r]));
#pragma unroll
                for (int msk = 1; msk < 16; msk <<= 1)
                    m0 = fmaxf(m0, __shfl_xor(m0, msk, 64));
                float mn = fmaxf(m_run[r], m0);
                float alpha = exp2f(m_run[r] - mn);
                m_run[r] = mn;
                float psum = 0.f;
#pragma unroll
                for (int jn = 0; jn < 4; jn++) {
                    float p = exp2f(sv[jn][r] - mn);
                    sv[jn][r] = p;
                    psum += p;
                }
#pragma unroll
                for (int msk = 1; msk < 16; msk <<= 1)
                    psum += __shfl_xor(psum, msk, 64);
                l_run[r] = l_run[r] * alpha + psum;
#pragma unroll
                for (int dt = 0; dt < 4; dt++)
                    o_acc[dt][r] *= alpha;
            }

            // P -> LDS (per-wave region; same-wave lgkmcnt ordering)
#pragma unroll
            for (int jn = 0; jn < 4; jn++)
#pragma unroll
                for (int r = 0; r < 4; r++) {
                    int row = q * 4 + r;
                    int pc = (2 * jn + (mr >> 3)) ^ (row & 7);
                    Ps[wv * 1024 + row * 64 + pc * 8 + (mr & 7)] = f2bf(sv[jn][r]);
                }
#pragma unroll
            for (int kk = 0; kk < 2; kk++) {
                bf16x8 ap = *(const bf16x8*)(&Ps[wv * 1024 + mr * 64 + (((kk * 4 + q) ^ m8) * 8)]);
#pragma unroll
                for (int dt = 0; dt < 4; dt++) {
                    bf16x8 bv = *(const bf16x8*)(&Vts[(dt * 16 + mr) * 64 + (((kk * 4 + q) ^ m8) * 8)]);
                    o_acc[dt] = __builtin_amdgcn_mfma_f32_16x16x32_bf16(ap, bv, o_acc[dt], 0, 0, 0);
                }
            }
        }

        if (!split) {
#pragma unroll
            for (int r = 0; r < 4; r++) {
                float inv = 1.0f / l_run[r];
                int trow = qt * 64 + wv * 16 + q * 4 + r;
                size_t obase = (size_t)(b * T_ + trow) * D_ + h * HD_;
#pragma unroll
                for (int dt = 0; dt < 4; dt++)
                    attn_out[obase + dt * 16 + mr] = f2bf(o_acc[dt][r] * inv);
            }
        } else {
            int s = (qt - 16) * 32 + bh;
            size_t pb = ((size_t)(s * 2 + half)) * 4096;
#pragma unroll
            for (int r = 0; r < 4; r++) {
                int row = wv * 16 + q * 4 + r;
#pragma unroll
                for (int dt = 0; dt < 4; dt++)
                    obuf[pb + (size_t)row * 64 + dt * 16 + mr] = f2bf(o_acc[dt][r]);
                if (mr == 0) {
                    mbuf[(s * 2 + half) * 64 + row] = m_run[r];
                    lbuf[(s * 2 + half) * 64 + row] = l_run[r];
                }
            }
        }
    }
}

// ---------------------------------------------------------------------------
// Kernel 3b: merge split-attention partials (flash combine, exp2 domain).
// ---------------------------------------------------------------------------
__global__ __launch_bounds__(256) void attn_merge_kernel(
    const __hip_bfloat16* __restrict__ obuf,
    const float* __restrict__ mbuf,
    const float* __restrict__ lbuf,
    __hip_bfloat16* __restrict__ attn_out)
{
    int s = blockIdx.x;             // 0..511
    int qt = 16 + (s >> 5);
    int bh = s & 31;
    int b = bh >> 4, h = bh & 15;
    int t = threadIdx.x;
    int row = t >> 2, c0 = (t & 3) * 16;
    float m0 = mbuf[(s * 2 + 0) * 64 + row], m1 = mbuf[(s * 2 + 1) * 64 + row];
    float l0 = lbuf[(s * 2 + 0) * 64 + row], l1 = lbuf[(s * 2 + 1) * 64 + row];
    float mm = fmaxf(m0, m1);
    float w0 = exp2f(m0 - mm), w1 = exp2f(m1 - mm);
    float inv = 1.0f / (l0 * w0 + l1 * w1);
    const __hip_bfloat16* p0 = obuf + ((size_t)(s * 2 + 0) * 64 + row) * 64 + c0;
    const __hip_bfloat16* p1 = obuf + ((size_t)(s * 2 + 1) * 64 + row) * 64 + c0;
    size_t ob = (size_t)(b * T_ + qt * 64 + row) * D_ + h * HD_ + c0;
#pragma unroll
    for (int c = 0; c < 16; c++)
        attn_out[ob + c] = f2bf((bf2f(p0[c]) * w0 + bf2f(p1[c]) * w1) * inv);
}

// ---------------------------------------------------------------------------
// Kernel 5: h = rmsnorm(xn,w2)*gamma+beta; rotations+silu; out = xn + r - h.
// ---------------------------------------------------------------------------
__global__ __launch_bounds__(256) void final_kernel(
    const float* __restrict__ xn,
    const float* __restrict__ gamma,
    const float* __restrict__ beta,
    const float* __restrict__ w2,
    const float* __restrict__ angles,
    const float* __restrict__ gate,
    const float* __restrict__ bias,
    const int* __restrict__ pi,
    const int* __restrict__ pj,
    const int* __restrict__ flag,
    void* __restrict__ outp)
{
    __shared__ float rbuf[D_];
    __shared__ float red[4];
    int row = blockIdx.x, t = threadIdx.x;
    int f = *flag;
    float eps = f ? 1.1920929e-7f : 0.0078125f;
    const float* xr = xn + (size_t)row * D_;
    float x4[4];
    float ss = 0.f;
#pragma unroll
    for (int c = 0; c < 4; c++) { x4[c] = xr[t * 4 + c]; ss += x4[c] * x4[c]; }
#pragma unroll
    for (int m = 32; m; m >>= 1) ss += __shfl_xor(ss, m, 64);
    int wv = t >> 6;
    if ((t & 63) == 0) red[wv] = ss;
    __syncthreads();
    float scale = rsqrtf((red[0] + red[1] + red[2] + red[3]) * (1.0f / D_) + eps);
    float hloc[4];
#pragma unroll
    for (int c = 0; c < 4; c++) {
        int e = t * 4 + c;
        float hv = x4[c] * scale * w2[e] * gamma[e] + beta[e];
        hloc[c] = hv;
        rbuf[e] = hv;
    }
    __syncthreads();
    for (int p = 0; p < NP_; p++) {
        float a = angles[p * P_ + t];
        float ca = __cosf(a), sa = __sinf(a);
        int ip = pi[p * P_ + t], jp = pj[p * P_ + t];
        float hi = rbuf[ip], hj = rbuf[jp];
        rbuf[ip] = hi * ca - hj * sa;
        rbuf[jp] = hi * sa + hj * ca;
        __syncthreads();
#pragma unroll
        for (int c = 0; c < 4; c++) {
            int e = t * 4 + c;
            float v = rbuf[e] * gate[p * D_ + e] + bias[p * D_ + e];
            rbuf[e] = v / (1.f + __expf(-v));
        }
        __syncthreads();
    }
#pragma unroll
    for (int c = 0; c < 4; c++) {
        int e = t * 4 + c;
        float ov = x4[c] + rbuf[e] - hloc[c];
        size_t idx = (size_t)row * D_ + e;
        if (f) ((float*)outp)[idx] = ov;
        else   ((__hip_bfloat16*)outp)[idx] = f2bf(ov);
    }
}

// ---------------------------------------------------------------------------
extern "C" void kernel_launch(void* const* d_in, const int* in_sizes, int n_in,
                              void* d_out, int out_size, void* d_ws, size_t ws_size,
                              hipStream_t stream)
{
    const void* x      = d_in[0];
    const void* gamma  = d_in[1];
    const void* beta   = d_in[2];
    const void* qkv_w  = d_in[3];
    const void* o_w    = d_in[4];
    const void* n1w    = d_in[5];
    const void* n2w    = d_in[6];
    const void* angles = d_in[7];
    const void* gate   = d_in[8];
    const void* bias   = d_in[9];
    const int* pi = (const int*)d_in[10];
    const int* pj = (const int*)d_in[11];

    const int M = B_ * T_;
    char* ws = (char*)d_ws;
    const size_t MB = 1u << 20;
    int*   flag    = (int*)ws;
    int*   counter = (int*)(ws + 2048);
    float* smalls  = (float*)(ws + 4096);      // 11008 floats, 44 KB
    float* gf   = smalls;
    float* bf   = smalls + 1024;
    float* n1f  = smalls + 2048;
    float* n2f  = smalls + 3072;
    float* angf = smalls + 4096;
    float* gtf  = smalls + 4864;
    float* bif  = smalls + 7936;
    float*          xf32 = (float*)         (ws +  1 * MB);  // 16 MB [M,D]
    __hip_bfloat16* wbf  = (__hip_bfloat16*)(ws + 17 * MB);  //  6 MB [3D,D]
    __hip_bfloat16* owbf = (__hip_bfloat16*)(ws + 23 * MB);  //  2 MB [D,D]
    __hip_bfloat16* h1   = (__hip_bfloat16*)(ws + 25 * MB);  //  8 MB [M,D] (h then attn-out)
    __hip_bfloat16* qkv  = (__hip_bfloat16*)(ws + 33 * MB);  // 24 MB [M,3D]
    float*          xnew = (float*)         (ws + 33 * MB);  // 16 MB, aliases dead qkv
    __hip_bfloat16* obuf = (__hip_bfloat16*)(ws + 57 * MB);  //  8 MB [512][2][64][64]
    float*          mbuf = (float*)         (ws + 65 * MB);  // 256 KB
    float*          lbuf = (float*)         (ws + 65 * MB + 512 * 1024);

    detect_kernel<<<1, 256, 0, stream>>>((const unsigned short*)x, flag, counter);

    cvt_small_kernel<<<43, 256, 0, stream>>>(gamma, beta, n1w, n2w, angles, gate, bias,
                                             smalls, flag);
    cvt16_kernel<<<(3 * D_ * D_ + 255) / 256, 256, 0, stream>>>(qkv_w, wbf, 3 * D_ * D_, flag);
    cvt16_kernel<<<(D_ * D_ + 255) / 256, 256, 0, stream>>>(o_w, owbf, D_ * D_, flag);

    rmsnorm1_kernel<<<M, 256, 0, stream>>>(x, gf, bf, n1f, flag, h1, xf32);

    gemm_bt_bf16_kernel<<<dim3(3 * D_ / 128, M / 128), 256, 0, stream>>>(
        h1, wbf, qkv, M, 3 * D_, D_);

    attn_kernel<<<1024, 256, 0, stream>>>(qkv, h1, counter, obuf, mbuf, lbuf);
    attn_merge_kernel<<<512, 256, 0, stream>>>(obuf, mbuf, lbuf, h1);

    gemm_bt_resid_kernel<<<dim3(D_ / 128, M / 128), 256, 0, stream>>>(
        h1, owbf, xf32, xnew, M, D_, D_);

    final_kernel<<<M, 256, 0, stream>>>(xnew, gf, bf, n2f, angf, gtf, bif,
                                        pi, pj, flag, d_out);
}